// Round 1
// baseline (549.016 us; speedup 1.0000x reference)
//
#include <hip/hip_runtime.h>
#include <cstdint>
#include <cstddef>

// ---------------------------------------------------------------------------
// DynamicMemoryCell on MI355X (gfx950)
//
// Math simplification: q_len = kv_len = 1 -> softmax over one key == 1.0
//   => attn == v, attention_weights == 1.0, and q/k/pm GEMMs are dead.
//
// Pipeline (all GEMMs are C = A @ W^T + b, W row-major [N,K] — "BT" layout):
//   cat   = bf16([prev_mem | input])               [B,2048]
//   pi    = cat[:,1024:] @ ip_w^T + ip_b           [B,1024] bf16
//   gated = prev * sigmoid(cat @ fg_w^T + fg_b)    [B,1024] bf16 (fused epi)
//   v     = pi @ wv^T + bv                         [B,1024] bf16
//   ctx   = v @ out_proj^T + out_proj_b            [B,1024] bf16
//   gi    = ctx @ gru_w_ih^T + gru_b_ih            [B,3072] bf16
//   gh    = gated @ gru_w_hh^T + gru_b_hh          [B,3072] bf16
//   upd   = GRU-combine(gi, gh, gated)             [B,1024] bf16
//   out   = upd * sigmoid(upd @ og_w^T + og_b)     [B,1024] f32 (fused epi)
//   attention weights output = 1.0f                [B]
// ---------------------------------------------------------------------------

typedef __bf16 bf16;
typedef bf16 bf16x4 __attribute__((ext_vector_type(4)));
typedef bf16 bf16x8 __attribute__((ext_vector_type(8)));
typedef float f32x4 __attribute__((ext_vector_type(4)));

#define B_ROWS 8192

__device__ __forceinline__ float sigmoid_f(float x) {
    return 1.0f / (1.0f + __expf(-x));
}
__device__ __forceinline__ float tanh_f(float x) {
    return 1.0f - 2.0f / (__expf(2.0f * x) + 1.0f);
}

// ---------------------------------------------------------------------------
// bf16 GEMM, C[M,N] = A[M,K] @ W[N,K]^T + bias, m97-style:
// 128x128 block tile, BK=32, 4 waves, each wave 64x64 via 4x4 mfma 16x16x32.
// global_load_lds width=16 staging (LDS layout row-major, no padding —
// required by the wave-uniform-base + lane*16 LDS write pattern).
//
// EPI: 0 = out_bf = bf16(acc + bias)
//      1 = out_bf = bf16( aux_f32 * sigmoid(acc + bias) )    (forget gate)
//      2 = out_f32 = float(aux_bf) * sigmoid(acc + bias)     (output gate)
// ---------------------------------------------------------------------------
template <int EPI>
__global__ __launch_bounds__(256, 2) void gemm_bt(
    const bf16* __restrict__ A, int lda,
    const bf16* __restrict__ W,   // [N,K], ldw == K
    const float* __restrict__ bias,
    int M, int N, int K,
    bf16* __restrict__ out_bf,
    float* __restrict__ out_f32,
    const float* __restrict__ aux_f32,
    const bf16* __restrict__ aux_bf)
{
    __shared__ bf16 sA[128 * 32];
    __shared__ bf16 sB[128 * 32];

    const int tid  = threadIdx.x;
    const int lane = tid & 63;
    const int wave = tid >> 6;
    const int wr   = (wave & 1) * 64;   // wave row offset within 128 tile
    const int wc   = (wave >> 1) * 64;  // wave col offset within 128 tile
    const int lrow = lane & 15;
    const int lq   = lane >> 4;

    const int brow = blockIdx.y * 128;
    const int bcol = blockIdx.x * 128;

    f32x4 acc[4][4];
#pragma unroll
    for (int i = 0; i < 4; ++i)
#pragma unroll
        for (int j = 0; j < 4; ++j) {
            f32x4 z = {0.0f, 0.0f, 0.0f, 0.0f};
            acc[i][j] = z;
        }

    for (int k0 = 0; k0 < K; k0 += 32) {
        // --- stage A tile: 128 rows x 32 bf16 = 512 x 16B chunks ---
#pragma unroll
        for (int i = 0; i < 2; ++i) {
            int c   = tid + i * 256;      // 0..511
            int row = c >> 2;             // 4 chunks per 64B row
            int col = (c & 3) << 3;       // element offset
            const bf16* gp = A + (size_t)(brow + row) * lda + (k0 + col);
            __builtin_amdgcn_global_load_lds(
                (const __attribute__((address_space(1))) void*)gp,
                (__attribute__((address_space(3))) void*)(&sA[c * 8]),
                16, 0, 0);
        }
        // --- stage W tile ---
#pragma unroll
        for (int i = 0; i < 2; ++i) {
            int c   = tid + i * 256;
            int row = c >> 2;
            int col = (c & 3) << 3;
            const bf16* gp = W + (size_t)(bcol + row) * K + (k0 + col);
            __builtin_amdgcn_global_load_lds(
                (const __attribute__((address_space(1))) void*)gp,
                (__attribute__((address_space(3))) void*)(&sB[c * 8]),
                16, 0, 0);
        }
        __syncthreads();

        // --- LDS -> fragments (ds_read_b128) ---
        bf16x8 av[4], bv[4];
#pragma unroll
        for (int i = 0; i < 4; ++i)
            av[i] = *(const bf16x8*)&sA[(wr + i * 16 + lrow) * 32 + lq * 8];
#pragma unroll
        for (int j = 0; j < 4; ++j)
            bv[j] = *(const bf16x8*)&sB[(wc + j * 16 + lrow) * 32 + lq * 8];

#pragma unroll
        for (int i = 0; i < 4; ++i)
#pragma unroll
            for (int j = 0; j < 4; ++j)
                acc[i][j] = __builtin_amdgcn_mfma_f32_16x16x32_bf16(
                    av[i], bv[j], acc[i][j], 0, 0, 0);

        __syncthreads();
    }

    // --- epilogue: C/D layout col = lane&15, row = (lane>>4)*4 + reg ---
#pragma unroll
    for (int j = 0; j < 4; ++j) {
        const int gcol = bcol + wc + j * 16 + lrow;
        const float bj = bias[gcol];
#pragma unroll
        for (int i = 0; i < 4; ++i) {
            const int growb = brow + wr + i * 16 + lq * 4;
#pragma unroll
            for (int r = 0; r < 4; ++r) {
                const size_t idx = (size_t)(growb + r) * N + gcol;
                const float val = acc[i][j][r] + bj;
                if (EPI == 0) {
                    out_bf[idx] = (bf16)val;
                } else if (EPI == 1) {
                    out_bf[idx] = (bf16)(aux_f32[idx] * sigmoid_f(val));
                } else {
                    out_f32[idx] = (float)aux_bf[idx] * sigmoid_f(val);
                }
            }
        }
    }
}

// ---------------------------------------------------------------------------
// Elementwise kernels
// ---------------------------------------------------------------------------

// dst[i] = bf16(src[i]); n must be a multiple of 1024 (grid = n/1024 blocks)
__global__ void cast_f32_bf16_k(const float* __restrict__ src,
                                bf16* __restrict__ dst, int n4) {
    int i = blockIdx.x * 256 + threadIdx.x;
    if (i >= n4) return;
    f32x4 v = ((const f32x4*)src)[i];
    bf16x4 o = {(bf16)v[0], (bf16)v[1], (bf16)v[2], (bf16)v[3]};
    ((bf16x4*)dst)[i] = o;
}

// cat[b, 0:1024] = bf16(mem[b]); cat[b, 1024:2048] = bf16(inp[b])
__global__ void build_cat_k(const float* __restrict__ mem,
                            const float* __restrict__ inp,
                            bf16* __restrict__ cat) {
    int i = blockIdx.x * 256 + threadIdx.x;  // float4 chunk id, 512 per row
    int row = i >> 9;
    int c4  = i & 511;
    f32x4 v;
    if (c4 < 256)
        v = ((const f32x4*)mem)[(size_t)row * 256 + c4];
    else
        v = ((const f32x4*)inp)[(size_t)row * 256 + (c4 - 256)];
    bf16x4 o = {(bf16)v[0], (bf16)v[1], (bf16)v[2], (bf16)v[3]};
    ((bf16x4*)cat)[i] = o;
}

// GRU combine: upd = (1-z)*n + z*gated,  r/z/n per PyTorch GRUCell
__global__ void gru_combine_k(const bf16* __restrict__ gi,
                              const bf16* __restrict__ gh,
                              const bf16* __restrict__ gated,
                              bf16* __restrict__ upd) {
    int i   = blockIdx.x * 256 + threadIdx.x;  // handles 8 elements
    int row = i >> 7;                          // 128 groups of 8 per row
    int c   = (i & 127) << 3;
    size_t b3 = (size_t)row * 3072 + c;
    size_t b1 = (size_t)row * 1024 + c;
    bf16x8 gir = *(const bf16x8*)(gi + b3);
    bf16x8 giz = *(const bf16x8*)(gi + b3 + 1024);
    bf16x8 gin = *(const bf16x8*)(gi + b3 + 2048);
    bf16x8 ghr = *(const bf16x8*)(gh + b3);
    bf16x8 ghz = *(const bf16x8*)(gh + b3 + 1024);
    bf16x8 ghn = *(const bf16x8*)(gh + b3 + 2048);
    bf16x8 g   = *(const bf16x8*)(gated + b1);
    bf16x8 o;
#pragma unroll
    for (int e = 0; e < 8; ++e) {
        float r = sigmoid_f((float)gir[e] + (float)ghr[e]);
        float z = sigmoid_f((float)giz[e] + (float)ghz[e]);
        float n = tanh_f((float)gin[e] + r * (float)ghn[e]);
        float u = (1.0f - z) * n + z * (float)g[e];
        o[e] = (bf16)u;
    }
    *(bf16x8*)(upd + b1) = o;
}

__global__ void fill_ones_k(float* __restrict__ p, int n) {
    int i = blockIdx.x * 256 + threadIdx.x;
    if (i < n) p[i] = 1.0f;
}

// ---------------------------------------------------------------------------
// Launch
// ---------------------------------------------------------------------------
extern "C" void kernel_launch(void* const* d_in, const int* in_sizes, int n_in,
                              void* d_out, int out_size, void* d_ws,
                              size_t ws_size, hipStream_t stream) {
    const float* input      = (const float*)d_in[0];
    const float* prev       = (const float*)d_in[1];
    const float* in_proj_w  = (const float*)d_in[2];
    const float* in_proj_b  = (const float*)d_in[3];
    const float* out_proj_w = (const float*)d_in[4];
    const float* out_proj_b = (const float*)d_in[5];
    const float* ip_w       = (const float*)d_in[6];
    const float* ip_b       = (const float*)d_in[7];
    // d_in[8]/d_in[9] (mp_w/mp_b) are dead: k is never used (softmax == 1)
    const float* fg_w  = (const float*)d_in[10];
    const float* fg_b  = (const float*)d_in[11];
    const float* og_w  = (const float*)d_in[12];
    const float* og_b  = (const float*)d_in[13];
    const float* gih_w = (const float*)d_in[14];
    const float* gih_b = (const float*)d_in[15];
    const float* ghh_w = (const float*)d_in[16];
    const float* ghh_b = (const float*)d_in[17];
    float* out = (float*)d_out;

    // ---- workspace layout (MiB offsets; overlaps respect dependency order)
    char* ws = (char*)d_ws;
    const size_t MB = 1024 * 1024;
    bf16* CAT   = (bf16*)(ws + 0);         // [B,2048] 32M; dead after pi/fg
    bf16* GI    = (bf16*)(ws + 0);         // [B,3072] 48M; overlaps CAT+V
    bf16* V     = (bf16*)(ws + 32 * MB);   // [B,1024] 16M; dead after ctx
    bf16* PI    = (bf16*)(ws + 48 * MB);   // [B,1024] 16M; then CTX, then UPD
    bf16* CTX   = PI;
    bf16* UPD   = PI;
    bf16* GATED = (bf16*)(ws + 64 * MB);   // [B,1024] 16M
    bf16* GH    = (bf16*)(ws + 80 * MB);   // [B,3072] 48M -> ends at 128M
    bf16* WIP   = (bf16*)(ws + 128 * MB);  // [1024,1024] 2M
    bf16* WV    = (bf16*)(ws + 130 * MB);  // [1024,1024] 2M
    bf16* WOP   = (bf16*)(ws + 132 * MB);  // [1024,1024] 2M
    bf16* WFG   = (bf16*)(ws + 134 * MB);  // [1024,2048] 4M
    bf16* WGIH  = (bf16*)(ws + 138 * MB);  // [3072,1024] 6M
    bf16* WGHH  = (bf16*)(ws + 144 * MB);  // [3072,1024] 6M
    bf16* WOG   = (bf16*)(ws + 150 * MB);  // [1024,1024] 2M -> total 152M

    const int M = B_ROWS;

    // ---- casts
    build_cat_k<<<dim3((M * 2048 / 4) / 256), dim3(256), 0, stream>>>(prev, input, CAT);
    cast_f32_bf16_k<<<dim3(1024), dim3(256), 0, stream>>>(ip_w, WIP, 1024 * 1024 / 4);
    cast_f32_bf16_k<<<dim3(1024), dim3(256), 0, stream>>>(in_proj_w + 2048 * 1024, WV, 1024 * 1024 / 4);
    cast_f32_bf16_k<<<dim3(1024), dim3(256), 0, stream>>>(out_proj_w, WOP, 1024 * 1024 / 4);
    cast_f32_bf16_k<<<dim3(2048), dim3(256), 0, stream>>>(fg_w, WFG, 1024 * 2048 / 4);
    cast_f32_bf16_k<<<dim3(3072), dim3(256), 0, stream>>>(gih_w, WGIH, 3072 * 1024 / 4);
    cast_f32_bf16_k<<<dim3(3072), dim3(256), 0, stream>>>(ghh_w, WGHH, 3072 * 1024 / 4);
    cast_f32_bf16_k<<<dim3(1024), dim3(256), 0, stream>>>(og_w, WOG, 1024 * 1024 / 4);

    dim3 blk(256);
    dim3 g1024(1024 / 128, M / 128);
    dim3 g3072(3072 / 128, M / 128);

    // pi = input @ ip_w^T + ip_b      (A = CAT cols 1024.., lda 2048)
    gemm_bt<0><<<g1024, blk, 0, stream>>>(CAT + 1024, 2048, WIP, ip_b,
                                          M, 1024, 1024, PI, nullptr, nullptr, nullptr);
    // gated = prev * sigmoid(cat @ fg_w^T + fg_b)
    gemm_bt<1><<<g1024, blk, 0, stream>>>(CAT, 2048, WFG, fg_b,
                                          M, 1024, 2048, GATED, nullptr, prev, nullptr);
    // v = pi @ wv^T + bv
    gemm_bt<0><<<g1024, blk, 0, stream>>>(PI, 1024, WV, in_proj_b + 2048,
                                          M, 1024, 1024, V, nullptr, nullptr, nullptr);
    // ctx = v @ out_proj^T + out_proj_b
    gemm_bt<0><<<g1024, blk, 0, stream>>>(V, 1024, WOP, out_proj_b,
                                          M, 1024, 1024, CTX, nullptr, nullptr, nullptr);
    // gi = ctx @ gru_w_ih^T + gru_b_ih
    gemm_bt<0><<<g3072, blk, 0, stream>>>(CTX, 1024, WGIH, gih_b,
                                          M, 3072, 1024, GI, nullptr, nullptr, nullptr);
    // gh = gated @ gru_w_hh^T + gru_b_hh
    gemm_bt<0><<<g3072, blk, 0, stream>>>(GATED, 1024, WGHH, ghh_b,
                                          M, 3072, 1024, GH, nullptr, nullptr, nullptr);
    // GRU combine
    gru_combine_k<<<dim3(M * 1024 / 8 / 256), blk, 0, stream>>>(GI, GH, GATED, UPD);
    // out = upd * sigmoid(upd @ og_w^T + og_b)   (fp32 straight to d_out)
    gemm_bt<2><<<g1024, blk, 0, stream>>>(UPD, 1024, WOG, og_b,
                                          M, 1024, 1024, nullptr, out, nullptr, UPD);
    // attention weights: softmax over a single key == 1.0
    fill_ones_k<<<dim3(32), blk, 0, stream>>>(out + (size_t)M * 1024, M);
}